// Round 1
// baseline (2727.190 us; speedup 1.0000x reference)
//
#include <hip/hip_runtime.h>
#include <cstddef>

// LSTM: x[64,512,512] f32, kernel[512,4096] f32, rec_kernel[1024,4096] f32,
// bias[4096] f32 -> h_last[64,1024] f32.
// Persistent kernel, weights stationary in VGPRs (bf16), fused x-projection.
// R3: fence-free steady state; relaxed agent-scope atomics for h/flags.
// R4 (this round): epilogue slimmed — gate math moved to wave0 only
// (each lane owns 4 consecutive u), h packed+stored straight from registers.
// Removes the hsh LDS round-trip and one __syncthreads per step; waves 1-3
// start the next step's x-part MFMAs while wave0 publishes.

namespace {
constexpr int cB = 64;
constexpr int cT = 512;
constexpr int cD = 512;
constexpr int cU = 1024;
constexpr int cG = 4096;   // 4*U
constexpr int NKC = 48;    // K/32 = 1536/32
constexpr int NBLK = 256;
constexpr int NT = 256;
constexpr int HSTR = 1032; // padded LDS h-row stride (bf16): 516 dwords, %32==4
}

typedef __attribute__((ext_vector_type(8))) short   short8;
typedef __attribute__((ext_vector_type(8))) __bf16  bf16x8;
typedef __attribute__((ext_vector_type(4))) float   f32x4;

__device__ inline short f2bf(float f) {
  unsigned u = __float_as_uint(f);
  u += 0x7fffu + ((u >> 16) & 1u);   // round-to-nearest-even
  return (short)(u >> 16);
}

__device__ inline f32x4 mfma16(short8 a, short8 b, f32x4 c) {
  return __builtin_amdgcn_mfma_f32_16x16x32_bf16(
      __builtin_bit_cast(bf16x8, a), __builtin_bit_cast(bf16x8, b), c, 0, 0, 0);
}

__device__ inline float sigm(float x) { return 1.0f / (1.0f + __expf(-x)); }
__device__ inline float tanh_(float x) {
  float a = fabsf(x);
  float e = __expf(-2.0f * a);
  float t = (1.0f - e) / (1.0f + e);
  return x < 0.0f ? -t : t;
}

__global__ __launch_bounds__(NT, 1) void lstm_persist(
    const float* __restrict__ x, const float* __restrict__ wk,
    const float* __restrict__ wr, const float* __restrict__ bias,
    float* __restrict__ out, short* __restrict__ xbf,
    short* h0, short* h1, unsigned* flags) {
  const int tid  = threadIdx.x;
  const int wave = tid >> 6;        // = gate id 0..3 (i,f,c,o)
  const int lane = tid & 63;
  const int n    = lane & 15;       // MFMA col within tile / A row m
  const int quad = lane >> 4;
  const int bid  = blockIdx.x;
  const int mt   = bid & 3;         // batch m-tile (16 rows each)
  const int cg   = bid >> 2;        // u-group 0..63 (16 u each)
  const int ub   = cg * 16;

  __shared__ short hlds[16 * HSTR]; // staged h rows (padded, ~33 KB)
  __shared__ float zsh[16 * 65];    // [row][gate*16+u], pad 65 = conflict-free

  // ---- phase 0: convert x to bf16 once (grid-stride) ----
  {
    const f32x4* xv = reinterpret_cast<const f32x4*>(x);
    short8* xo = reinterpret_cast<short8*>(xbf);
    const size_t nvec = (size_t)cB * cT * cD / 8;
    for (size_t i = (size_t)bid * NT + tid; i < nvec; i += (size_t)NBLK * NT) {
      f32x4 v0 = xv[2 * i];
      f32x4 v1 = xv[2 * i + 1];
      short8 s;
      s[0] = f2bf(v0[0]); s[1] = f2bf(v0[1]); s[2] = f2bf(v0[2]); s[3] = f2bf(v0[3]);
      s[4] = f2bf(v1[0]); s[5] = f2bf(v1[1]); s[6] = f2bf(v1[2]); s[7] = f2bf(v1[3]);
      xo[i] = s;
    }
  }

  // ---- load time-invariant W fragments into registers ----
  // B-frag layout (16x16x32 bf16): B[k][n], n = lane&15, k = quad*8 + j.
  short8 Bf[NKC];
  {
    const int col = wave * cU + ub + n;     // column in the 4096 gate dim
    #pragma unroll
    for (int kc = 0; kc < NKC; ++kc) {
      const int k0 = kc * 32 + quad * 8;
      short8 b;
      #pragma unroll
      for (int j = 0; j < 8; ++j) {
        const int k = k0 + j;
        const float w = (k < cD) ? wk[(size_t)k * cG + col]
                                 : wr[(size_t)(k - cD) * cG + col];
        b[j] = f2bf(w);
      }
      Bf[kc] = b;
    }
  }

  // ---- wave0-only epilogue state: lane -> (row = lane>>2, u = uc..uc+3) ----
  const int erow = lane >> 2;       // 0..15
  const int echk = lane & 3;        // 8B chunk within the block's 16-u slice
  const int euc  = echk * 4;        // local u offset 0,4,8,12
  f32x4 bI = {0,0,0,0}, bF = {0,0,0,0}, bC = {0,0,0,0}, bO = {0,0,0,0};
  f32x4 cst = {0,0,0,0};
  if (wave == 0) {
    bI = *reinterpret_cast<const f32x4*>(bias + 0 * cU + ub + euc);
    bF = *reinterpret_cast<const f32x4*>(bias + 1 * cU + ub + euc);
    bC = *reinterpret_cast<const f32x4*>(bias + 2 * cU + ub + euc);
    bO = *reinterpret_cast<const f32x4*>(bias + 3 * cU + ub + euc);
  }

  // A-frag addressing for x: A[m][k], m = lane&15 -> batch row, k = quad*8+j
  const int brow = mt * 16 + n;
  const short* xrow = xbf + (size_t)brow * cT * cD + quad * 8;

  // ---- initial full-grid barrier (epoch 1): xbf ready everywhere ----
  // One-time fences are fine; the steady-state loop below is fence-free.
  __builtin_amdgcn_fence(__ATOMIC_RELEASE, "agent");
  __syncthreads();
  if (tid == 0)
    __hip_atomic_store(flags + bid * 16, 1u, __ATOMIC_RELEASE,
                       __HIP_MEMORY_SCOPE_AGENT);
  if (wave == 0) {
    #pragma unroll
    for (int j = 0; j < 4; ++j) {
      const unsigned* fp = flags + (j * 64 + lane) * 16;
      while (__hip_atomic_load(fp, __ATOMIC_RELAXED,
                               __HIP_MEMORY_SCOPE_AGENT) < 1u) {}
    }
  }
  __syncthreads();
  __builtin_amdgcn_fence(__ATOMIC_ACQUIRE, "agent");

  const unsigned long long* hp64 = (const unsigned long long*)h0;
  unsigned long long* hn64 = (unsigned long long*)h1;
  unsigned long long* hlds64 = (unsigned long long*)hlds;

  for (int t = 0; t < cT; ++t) {
    // x-part of K (h-independent) — overlaps the flag wait below
    f32x4 acc[4] = {{0,0,0,0},{0,0,0,0},{0,0,0,0},{0,0,0,0}};
    const short* xr = xrow + (size_t)t * cD;
    #pragma unroll
    for (int kc = 0; kc < 16; ++kc) {
      short8 af = *reinterpret_cast<const short8*>(xr + kc * 32);
      acc[kc & 3] = mfma16(af, Bf[kc], acc[kc & 3]);
    }

    if (t > 0) {
      // wait for all 64 producers of our mt group to publish h_t
      if (wave == 0) {
        const unsigned* fp = flags + ((lane << 2) + mt) * 16;
        const unsigned e = (unsigned)t + 1u;
        while (__hip_atomic_load(fp, __ATOMIC_RELAXED,
                                 __HIP_MEMORY_SCOPE_AGENT) < e) {}
      }
      __syncthreads();
    }

    // stage our 16 h rows (32 KB) into LDS via MALL-coherent 8B loads:
    // round r covers row mt*16+r; thread tid loads chunk tid (256 chunks/row)
    {
      unsigned long long tmp[16];
      const unsigned long long* src = hp64 + (size_t)(mt * 16) * 256 + tid;
      #pragma unroll
      for (int r = 0; r < 16; ++r)
        tmp[r] = __hip_atomic_load(src + r * 256, __ATOMIC_RELAXED,
                                   __HIP_MEMORY_SCOPE_AGENT);
      unsigned long long* dst = hlds64 + tid;   // row stride 258 (8B units)
      #pragma unroll
      for (int r = 0; r < 16; ++r) dst[r * 258] = tmp[r];
    }
    __syncthreads();

    // h-part MFMAs from LDS (A row = n, k = kc*32 + quad*8 + j)
    const short* hfrag = hlds + n * HSTR + quad * 8;
    #pragma unroll
    for (int kc = 0; kc < 32; ++kc) {
      short8 af = *reinterpret_cast<const short8*>(hfrag + kc * 32);
      acc[kc & 3] = mfma16(af, Bf[16 + kc], acc[kc & 3]);
    }
    f32x4 z4 = (acc[0] + acc[1]) + (acc[2] + acc[3]);

    // C/D layout: col = lane&15, row = quad*4 + reg
    #pragma unroll
    for (int r = 0; r < 4; ++r)
      zsh[(quad * 4 + r) * 65 + wave * 16 + n] = z4[r];
    __syncthreads();

    // ---- wave0-only epilogue: gate math + pack + publish ----
    // zsh(t) is safe until the staging barrier of t+1, which wave0 only
    // reaches after finishing here; waves 1-3 run ahead into t+1's x-part.
    if (wave == 0) {
      const float* zr = zsh + erow * 65;
      float hv[4];
      #pragma unroll
      for (int j = 0; j < 4; ++j) {
        float ig = sigm(zr[euc + j]       + bI[j]);
        float fg = sigm(zr[16 + euc + j]  + bF[j]);
        float gg = tanh_(zr[32 + euc + j] + bC[j]);
        float og = sigm(zr[48 + euc + j]  + bO[j]);
        cst[j] = fg * cst[j] + ig * gg;
        hv[j] = og * tanh_(cst[j]);
      }
      if (t == cT - 1) {
        f32x4 o4 = {hv[0], hv[1], hv[2], hv[3]};
        *reinterpret_cast<f32x4*>(
            &out[(size_t)(mt * 16 + erow) * cU + ub + euc]) = o4;
      } else {
        union { short s[4]; unsigned long long v; } pk;
        pk.s[0] = f2bf(hv[0]); pk.s[1] = f2bf(hv[1]);
        pk.s[2] = f2bf(hv[2]); pk.s[3] = f2bf(hv[3]);
        __hip_atomic_store(hn64 + (size_t)(mt * 16 + erow) * 256 + cg * 4 + echk,
                           pk.v, __ATOMIC_RELAXED, __HIP_MEMORY_SCOPE_AGENT);
        // drain stores to the coherency point, then publish the flag.
        asm volatile("s_waitcnt vmcnt(0)" ::: "memory");
        if (lane == 0)
          __hip_atomic_store(flags + bid * 16, (unsigned)(t + 2),
                             __ATOMIC_RELAXED, __HIP_MEMORY_SCOPE_AGENT);
      }
    }
    if (t != cT - 1) {
      const unsigned long long* tmp = hn64;
      hn64 = (unsigned long long*)hp64;
      hp64 = tmp;
    }
  }
}

extern "C" void kernel_launch(void* const* d_in, const int* in_sizes, int n_in,
                              void* d_out, int out_size, void* d_ws, size_t ws_size,
                              hipStream_t stream) {
  const float* x    = (const float*)d_in[0];
  const float* wk   = (const float*)d_in[1];
  const float* wr   = (const float*)d_in[2];
  const float* bias = (const float*)d_in[3];
  float* out = (float*)d_out;

  char* ws = (char*)d_ws;
  unsigned* flags = (unsigned*)ws;                     // 256 slots x 64B = 16 KB
  short* h0  = (short*)(ws + 16384);                   // 2 x 64*1024 bf16
  short* h1  = h0 + (size_t)cB * cU;
  short* xbf = (short*)(ws + 16384 + 2 * (size_t)cB * cU * 2);  // x bf16, 32 MB

  // zero: flags + h0 (initial hidden state). ws is poisoned 0xAA each call.
  hipMemsetAsync(ws, 0, 16384 + (size_t)cB * cU * 2, stream);

  lstm_persist<<<dim3(NBLK), dim3(NT), 0, stream>>>(
      x, wk, wr, bias, out, xbf, h0, h1, flags);
}